// Round 2
// baseline (23797.818 us; speedup 1.0000x reference)
//
#include <hip/hip_runtime.h>
#include <hip/hip_bf16.h>
#include <stdint.h>

#define HD   512   // hidden dim H
#define ID   128   // input dim I
#define NCLS 100   // num classes
#define TT   512   // sequence length T
#define BB   128   // batch B
#define NEMB 101   // NC + 1 embedding rows

// workspace layout (bytes)
#define WS_FLAG 0              // int mode flag: 0 = f32 inputs, 1 = bf16 inputs
#define WS_G    4096           // float G[101][2048]          (808 KB)
#define WS_WCT  (1u << 20)     // WcT: bf16 mode 1.5 MB / f32 mode 3 MB

using bf16 = __hip_bfloat16;

__device__ __forceinline__ float b2f(bf16 v) { return __bfloat162float(v); }
__device__ __forceinline__ float sigf(float x) { return 1.0f / (1.0f + __expf(-x)); }
// unpack 2 bf16 (packed in a uint32, little-endian) to 2 f32 — exact
__device__ __forceinline__ float2 upk(unsigned int u) {
    float2 r;
    r.x = __uint_as_float(u << 16);
    r.y = __uint_as_float(u & 0xFFFF0000u);
    return r;
}

template <bool BF>
__device__ __forceinline__ float ldv(const void* p, int i) {
    if constexpr (BF) return b2f(((const bf16*)p)[i]);
    else              return ((const float*)p)[i];
}

// ---------------------------------------------------------------------------
// Dtype sniffer. emb row 0 is exactly 0.0 by construction. Bytes [256,512):
//   f32  -> still row 0 -> all zero
//   bf16 -> row 1 (128 random normals) -> nonzero
// ---------------------------------------------------------------------------
__global__ void detect_mode(const uint32_t* __restrict__ emb_raw, int* __restrict__ flag) {
    if (threadIdx.x == 0) {
        uint32_t acc = 0;
        for (int i = 64; i < 128; ++i) acc |= emb_raw[i];
        *flag = (acc == 0u) ? 0 : 1;
    }
}

// ---------------------------------------------------------------------------
// G[c][j], c in [0,101), j in [0,2048): input-side gate pre-activations per
// embedding class. j = q*512 + col, q in {0:f, 1:i, 2:o, 3:ctilde}; the
// ctilde quarter is pre-sigmoided (it never receives a cg contribution).
// ---------------------------------------------------------------------------
template <bool BF>
__global__ void build_G(const int* __restrict__ flag,
                        const void* __restrict__ emb,
                        const void* __restrict__ Wfx, const void* __restrict__ Wix,
                        const void* __restrict__ Wox, const void* __restrict__ Wcx,
                        const void* __restrict__ bfv, const void* __restrict__ biv,
                        const void* __restrict__ bov, const void* __restrict__ bcv,
                        float* __restrict__ G) {
    if (*flag != (BF ? 1 : 0)) return;
    const int c   = blockIdx.x;                     // 0..100
    const int j   = blockIdx.y * 256 + threadIdx.x; // 0..2047
    const int q   = j >> 9;
    const int col = j & 511;
    const void* W  = (q == 0) ? Wfx : (q == 1) ? Wix : (q == 2) ? Wox : Wcx;
    const void* bv = (q == 0) ? bfv : (q == 1) ? biv : (q == 2) ? bov : bcv;
    float acc = ldv<BF>(bv, col);
    for (int i = 0; i < ID; ++i)
        acc += ldv<BF>(emb, c * ID + i) * ldv<BF>(W, i * HD + col);
    if (q == 3) acc = sigf(acc);
    G[c * 2048 + j] = acc;
}

// ---------------------------------------------------------------------------
// WcT[j][h] = Wc[h][j], column-major view of concat([Wfc,Wic,Woc],1).
// Stored in the INPUT precision (bf16 or f32) so it is exact.
// ---------------------------------------------------------------------------
template <bool BF>
__global__ void build_WcT(const int* __restrict__ flag,
                          const void* __restrict__ Wfc, const void* __restrict__ Wic,
                          const void* __restrict__ Woc, void* __restrict__ WcT) {
    if (*flag != (BF ? 1 : 0)) return;
    const int gid = blockIdx.x * 256 + threadIdx.x; // < 1536*512
    const int j = gid >> 9;                          // Wc column, 0..1535
    const int h = gid & 511;
    const void* W = (j < 512) ? Wfc : (j < 1024) ? Wic : Woc;
    const int jj = j & 511;
    const float v = ldv<BF>(W, h * HD + jj);
    if constexpr (BF) ((bf16*)WcT)[(size_t)j * HD + h] = __float2bfloat16(v);
    else              ((float*)WcT)[(size_t)j * HD + h] = v;
}

// ---------------------------------------------------------------------------
// One workgroup per batch row. C lives in LDS (f32). Thread j owns f-col j
// and i-col j every step; o-col j only at the final step (h is dead state —
// only h[T-1] feeds the projection). Starts after the last reset (C==0 there,
// r==1 afterwards). Ends with the class projection + log_softmax for its row.
// ---------------------------------------------------------------------------
template <bool BF>
__global__ __launch_bounds__(HD) void recur(
    const int*  __restrict__ flag, const int*  __restrict__ x,
    const float* __restrict__ G,   const void* __restrict__ WcT,
    const void* __restrict__ Wph,  const void* __restrict__ bp,
    void* __restrict__ out)
{
    if (*flag != (BF ? 1 : 0)) return;

    __shared__ __align__(16) float C_s[HD];
    __shared__ __align__(16) float h_s[HD];
    __shared__ int   idx_s[TT];
    __shared__ float p_s[NCLS];
    __shared__ float lse_s;
    __shared__ int   lastz;

    const int b   = blockIdx.x;
    const int tid = threadIdx.x;

    idx_s[tid] = x[b * TT + tid];
    if (tid == 0) lastz = -1;
    C_s[tid] = 0.0f;
    __syncthreads();
    if (idx_s[tid] == 0) atomicMax(&lastz, tid);
    __syncthreads();
    const int t0 = lastz + 1;   // C is exactly 0 entering t0; r==1 afterwards

    float h_val = 0.0f;
    const float4* C4 = reinterpret_cast<const float4*>(C_s);

    // per-thread weight row pointers
    const uint4*  wfB = nullptr; const uint4*  wiB = nullptr; const uint4*  woB = nullptr;
    const float4* wfF = nullptr; const float4* wiF = nullptr; const float4* woF = nullptr;
    if constexpr (BF) {
        const bf16* W = (const bf16*)WcT;
        wfB = reinterpret_cast<const uint4*>(W + (size_t)tid * HD);
        wiB = reinterpret_cast<const uint4*>(W + (size_t)(HD + tid) * HD);
        woB = reinterpret_cast<const uint4*>(W + (size_t)(2 * HD + tid) * HD);
    } else {
        const float* W = (const float*)WcT;
        wfF = reinterpret_cast<const float4*>(W + (size_t)tid * HD);
        wiF = reinterpret_cast<const float4*>(W + (size_t)(HD + tid) * HD);
        woF = reinterpret_cast<const float4*>(W + (size_t)(2 * HD + tid) * HD);
    }

    for (int t = t0; t < TT; ++t) {
        const int c = idx_s[t];
        const float* Grow = G + c * 2048;
        const float gf  = Grow[tid];
        const float gi  = Grow[HD + tid];
        const float sgc = Grow[3 * HD + tid];   // pre-sigmoided ctilde

        float accf = 0.0f, acci = 0.0f;
        if constexpr (BF) {
            #pragma unroll 4
            for (int hh = 0; hh < 64; ++hh) {
                const uint4 af = wfB[hh];
                const uint4 ai = wiB[hh];
                const float4 c0 = C4[2 * hh];
                const float4 c1 = C4[2 * hh + 1];
                float2 u;
                u = upk(af.x); accf += c0.x * u.x + c0.y * u.y;
                u = upk(af.y); accf += c0.z * u.x + c0.w * u.y;
                u = upk(af.z); accf += c1.x * u.x + c1.y * u.y;
                u = upk(af.w); accf += c1.z * u.x + c1.w * u.y;
                u = upk(ai.x); acci += c0.x * u.x + c0.y * u.y;
                u = upk(ai.y); acci += c0.z * u.x + c0.w * u.y;
                u = upk(ai.z); acci += c1.x * u.x + c1.y * u.y;
                u = upk(ai.w); acci += c1.z * u.x + c1.w * u.y;
            }
        } else {
            #pragma unroll 4
            for (int hh = 0; hh < 128; ++hh) {
                const float4 af = wfF[hh];
                const float4 ai = wiF[hh];
                const float4 cc = C4[hh];
                accf += af.x * cc.x + af.y * cc.y + af.z * cc.z + af.w * cc.w;
                acci += ai.x * cc.x + ai.y * cc.y + ai.z * cc.z + ai.w * cc.w;
            }
        }

        const bool last = (t == TT - 1);
        float acco = 0.0f;
        if (last) {
            if constexpr (BF) {
                #pragma unroll 4
                for (int hh = 0; hh < 64; ++hh) {
                    const uint4 ao = woB[hh];
                    const float4 c0 = C4[2 * hh];
                    const float4 c1 = C4[2 * hh + 1];
                    float2 u;
                    u = upk(ao.x); acco += c0.x * u.x + c0.y * u.y;
                    u = upk(ao.y); acco += c0.z * u.x + c0.w * u.y;
                    u = upk(ao.z); acco += c1.x * u.x + c1.y * u.y;
                    u = upk(ao.w); acco += c1.z * u.x + c1.w * u.y;
                }
            } else {
                #pragma unroll 4
                for (int hh = 0; hh < 128; ++hh) {
                    const float4 ao = woF[hh];
                    const float4 cc = C4[hh];
                    acco += ao.x * cc.x + ao.y * cc.y + ao.z * cc.z + ao.w * cc.w;
                }
            }
        }

        const float oldC = C_s[tid];
        __syncthreads();                    // all reads of C done before update
        const float f  = sigf(gf + accf);
        const float ii = sigf(gi + acci);
        const float Cn = sgc * ii + oldC * f;   // r == 1 in the simulated range
        C_s[tid] = Cn;
        if (last) {
            const float go = Grow[2 * HD + tid];
            const float o  = sigf(go + acco);
            h_val = tanhf(Cn) * o;
        }
        __syncthreads();
    }

    h_s[tid] = h_val;                       // 0 if row ends in a reset / no steps
    __syncthreads();

    if (tid < NCLS) {
        float p = ldv<BF>(bp, tid);
        for (int hh = 0; hh < HD; ++hh)
            p += h_s[hh] * ldv<BF>(Wph, hh * NCLS + tid);
        p_s[tid] = p;
    }
    __syncthreads();
    if (tid == 0) {
        float m = -1e30f;
        for (int n = 0; n < NCLS; ++n) m = fmaxf(m, p_s[n]);
        float s = 0.0f;
        for (int n = 0; n < NCLS; ++n) s += __expf(p_s[n] - m);
        lse_s = m + __logf(s);
    }
    __syncthreads();
    if (tid < NCLS) {
        const float v = p_s[tid] - lse_s;
        if constexpr (BF) ((bf16*)out)[b * NCLS + tid] = __float2bfloat16(v);
        else              ((float*)out)[b * NCLS + tid] = v;
    }
}

// ---------------------------------------------------------------------------
extern "C" void kernel_launch(void* const* d_in, const int* in_sizes, int n_in,
                              void* d_out, int out_size, void* d_ws, size_t ws_size,
                              hipStream_t stream) {
    const int* x   = (const int*)d_in[0];
    const void* emb = d_in[1];
    const void* Wfx = d_in[2];
    const void* Wfc = d_in[3];
    const void* bfv = d_in[4];
    const void* Wix = d_in[5];
    const void* Wic = d_in[6];
    const void* biv = d_in[7];
    const void* Wox = d_in[8];
    const void* Woc = d_in[9];
    const void* bov = d_in[10];
    const void* Wcx = d_in[11];
    const void* bcv = d_in[12];
    const void* Wph = d_in[13];
    const void* bp  = d_in[14];

    int*   flag = (int*)d_ws;
    float* G    = (float*)((char*)d_ws + WS_G);
    void*  WcT  = (void*)((char*)d_ws + WS_WCT);

    detect_mode<<<1, 64, 0, stream>>>((const uint32_t*)emb, flag);

    build_G<false><<<dim3(NEMB, 8), 256, 0, stream>>>(flag, emb, Wfx, Wix, Wox, Wcx,
                                                      bfv, biv, bov, bcv, G);
    build_G<true ><<<dim3(NEMB, 8), 256, 0, stream>>>(flag, emb, Wfx, Wix, Wox, Wcx,
                                                      bfv, biv, bov, bcv, G);

    build_WcT<false><<<dim3((1536 * 512) / 256), 256, 0, stream>>>(flag, Wfc, Wic, Woc, WcT);
    build_WcT<true ><<<dim3((1536 * 512) / 256), 256, 0, stream>>>(flag, Wfc, Wic, Woc, WcT);

    recur<false><<<BB, HD, 0, stream>>>(flag, x, G, WcT, Wph, bp, d_out);
    recur<true ><<<BB, HD, 0, stream>>>(flag, x, G, WcT, Wph, bp, d_out);
}